// Round 9
// baseline (497.013 us; speedup 1.0000x reference)
//
#include <hip/hip_runtime.h>
#include <math.h>

typedef __attribute__((ext_vector_type(8))) short short8;
typedef __attribute__((ext_vector_type(4))) float floatx4;
typedef __attribute__((ext_vector_type(4))) unsigned int uintx4;
typedef __attribute__((ext_vector_type(2))) unsigned int uintx2;

#define MFMA16(a, b, c) __builtin_amdgcn_mfma_f32_16x16x32_bf16((a), (b), (c), 0, 0, 0)

// log2(e) * (1/sqrt(64)) — folded into Q so attention works in exp2 domain
#define QSCALE 0.18033688011112042f

__device__ __forceinline__ unsigned short f2bf(float x) {
    unsigned int u = __float_as_uint(x);
    u += 0x7fffu + ((u >> 16) & 1u);   // round-to-nearest-even
    return (unsigned short)(u >> 16);
}

__device__ __forceinline__ short8 lds8(const unsigned short* p) {
    return *reinterpret_cast<const short8*>(p);
}

// async global->LDS, 16B per lane; LDS dest = wave-uniform base + lane*16
__device__ __forceinline__ void g2l16(const unsigned short* g, unsigned short* l) {
    __builtin_amdgcn_global_load_lds(
        (const __attribute__((address_space(1))) unsigned int*)g,
        (__attribute__((address_space(3))) unsigned int*)l,
        16, 0, 0);
}

// pack two f32 -> bf16x2 dword (RNE): low = a, high = b
__device__ __forceinline__ unsigned int cvtpk(float a, float b) {
    unsigned int r;
    asm("v_cvt_pk_bf16_f32 %0, %1, %2" : "=v"(r) : "v"(a), "v"(b));
    return r;
}

// swap lanes[32:63] of a with lanes[0:31] of b (both modified)
__device__ __forceinline__ void pl32swap(unsigned int& a, unsigned int& b) {
    asm("v_permlane32_swap_b32 %0, %1" : "+v"(a), "+v"(b));
}

// swap odd 16-lane groups of a with even 16-lane groups of b (both modified)
__device__ __forceinline__ void pl16swap(unsigned int& a, unsigned int& b) {
    asm("v_permlane16_swap_b32 %0, %1" : "+v"(a), "+v"(b));
}

// ---------------- prep: fp32 -> bf16 convert (vectorized) ----------------
__global__ void cvt_bf16(const float* __restrict__ src, unsigned short* __restrict__ dst, int n4) {
    int i = blockIdx.x * blockDim.x + threadIdx.x;
    if (i >= n4) return;
    float4 v = reinterpret_cast<const float4*>(src)[i];
    ushort4 o;
    o.x = f2bf(v.x); o.y = f2bf(v.y); o.z = f2bf(v.z); o.w = f2bf(v.w);
    reinterpret_cast<ushort4*>(dst)[i] = o;
}

// ---------------- prep: K window convert (coalesced both sides) ----------------
__global__ void prep_k(const float* __restrict__ kc, unsigned short* __restrict__ Kw) {
    int i = blockIdx.x * blockDim.x + threadIdx.x;   // 0 .. 262143
    int d4  = (i & 15) * 4;
    int s   = (i >> 4) & 1023;
    int bkv = i >> 14;
    size_t src = ((size_t)bkv * 4096 + 3072 + s) * 64 + d4;
    float4 kv = *reinterpret_cast<const float4*>(kc + src);
    ushort4 ko;
    ko.x = f2bf(kv.x); ko.y = f2bf(kv.y); ko.z = f2bf(kv.z); ko.w = f2bf(kv.w);
    *reinterpret_cast<ushort4*>(Kw + ((size_t)bkv * 1024 + s) * 64 + d4) = ko;
}

// ---------------- prep: V window transpose via LDS tile ----------------
__global__ void prep_v(const float* __restrict__ vc, unsigned short* __restrict__ Vt) {
    __shared__ unsigned short tl[64][72];
    const int bkv = blockIdx.x >> 4;
    const int s0  = (blockIdx.x & 15) * 64;
    const int t   = threadIdx.x;
    const int sl  = t >> 2;
    const int dq  = (t & 3) * 16;
    const float* src = vc + ((size_t)bkv * 4096 + 3072 + s0 + sl) * 64 + dq;
    float4 v0 = reinterpret_cast<const float4*>(src)[0];
    float4 v1 = reinterpret_cast<const float4*>(src)[1];
    float4 v2 = reinterpret_cast<const float4*>(src)[2];
    float4 v3 = reinterpret_cast<const float4*>(src)[3];
    tl[dq +  0][sl] = f2bf(v0.x); tl[dq +  1][sl] = f2bf(v0.y);
    tl[dq +  2][sl] = f2bf(v0.z); tl[dq +  3][sl] = f2bf(v0.w);
    tl[dq +  4][sl] = f2bf(v1.x); tl[dq +  5][sl] = f2bf(v1.y);
    tl[dq +  6][sl] = f2bf(v1.z); tl[dq +  7][sl] = f2bf(v1.w);
    tl[dq +  8][sl] = f2bf(v2.x); tl[dq +  9][sl] = f2bf(v2.y);
    tl[dq + 10][sl] = f2bf(v2.z); tl[dq + 11][sl] = f2bf(v2.w);
    tl[dq + 12][sl] = f2bf(v3.x); tl[dq + 13][sl] = f2bf(v3.y);
    tl[dq + 14][sl] = f2bf(v3.z); tl[dq + 15][sl] = f2bf(v3.w);
    __syncthreads();
    const int dl = t >> 2;
    const int sc = (t & 3) * 16;
    unsigned short* dst = Vt + ((size_t)bkv * 64 + dl) * 1024 + s0 + sc;
    short8 x0 = *reinterpret_cast<const short8*>(&tl[dl][sc]);
    short8 x1 = *reinterpret_cast<const short8*>(&tl[dl][sc + 8]);
    *reinterpret_cast<short8*>(dst)     = x0;
    *reinterpret_cast<short8*>(dst + 8) = x1;
}

// ---------------- bf16 MFMA GEMM, 128x256 tile, BK=32, 8 waves, 2 blocks/CU ----------------
// Occupancy-first redesign: 48 KiB LDS (2 bufs x {A 8KB + B 16KB}) + VGPR<=128
// (__launch_bounds__(512,4)) -> 2 independent blocks per CU = 4 waves/SIMD.
// Barrier convoys of one block hide under the other block's work (the R3->R4
// attn mechanism). Counted-vmcnt pipeline: stage tile t+2 during compute of t,
// wait only t+1 (vmcnt(3)) at iteration end. Fragment-order LDS: g2l16 linear
// dest + lane-linear ds_read_b128, conflict-free by construction.
// Wave (wr = wid>>2, wc = wid&3) owns a 64x64 sub-tile: acc[4][4] = 64 VGPR.
template <int EPI>
__global__ __launch_bounds__(512, 4)
void gemm128(const unsigned short* __restrict__ A,
             const unsigned short* __restrict__ Bt,
             float* __restrict__ Cf,
             unsigned short* __restrict__ Cb) {
    constexpr int K  = 2048;
    constexpr int NT = 64;                        // K / 32
    __shared__ __align__(16) unsigned short sm[24576];   // 48 KiB

    const int tid  = threadIdx.x;
    const int lane = tid & 63;
    const int l15  = lane & 15;
    const int quad = lane >> 4;
    const int wid  = tid >> 6;                    // 0..7
    const int wr   = wid >> 2;                    // 0..1 (M half: 64 rows)
    const int wc   = wid & 3;                     // 0..3 (N quarter: 64 cols)

    const int bn = blockIdx.x & 7;                // XCD-friendly: B-panel per XCD (1 MB, L2)
    const int bm = blockIdx.x >> 3;               // 0..63

    // staging sources: wave w stages A rows w*16+l15, B rows w*16+l15 and 128+w*16+l15
    const unsigned short* gA0 = A  + (size_t)(bm * 128 + wid * 16 + l15) * K + quad * 8;
    const unsigned short* gB0 = Bt + (size_t)(bn * 256 + wid * 16 + l15) * K + quad * 8;
    const unsigned short* gB1 = gB0 + (size_t)128 * K;

    auto STAGE = [&](int t) {
        unsigned short* dst = sm + (t & 1) * 12288;
        const int off = t * 32;
        g2l16(gA0 + off, dst + wid * 512);                 // A frags 0..7
        g2l16(gB0 + off, dst + 4096 + wid * 512);          // B frags 0..7
        g2l16(gB1 + off, dst + 8192 + wid * 512);          // B frags 8..15
    };

    floatx4 acc[4][4];
#pragma unroll
    for (int i = 0; i < 4; ++i)
#pragma unroll
        for (int j = 0; j < 4; ++j) acc[i][j] = floatx4{0, 0, 0, 0};

    STAGE(0);
    STAGE(1);
    asm volatile("s_waitcnt vmcnt(3)" ::: "memory");
    __builtin_amdgcn_s_barrier();
    asm volatile("" ::: "memory");

    for (int t = 0; t < NT; ++t) {
        const unsigned short* cb = sm + (t & 1) * 12288;

        short8 af[4], bf[4];
#pragma unroll
        for (int i = 0; i < 4; ++i)
            af[i] = lds8(cb + (wr * 4 + i) * 512 + lane * 8);
#pragma unroll
        for (int j = 0; j < 4; ++j)
            bf[j] = lds8(cb + 4096 + (wc * 4 + j) * 512 + lane * 8);

        asm volatile("s_waitcnt lgkmcnt(0)" ::: "memory");
        __builtin_amdgcn_s_barrier();             // all reads of tile t retired
        asm volatile("" ::: "memory");

        if (t + 2 < NT) STAGE(t + 2);             // overwrite dead buf[t&1]

        __builtin_amdgcn_s_setprio(1);
#pragma unroll
        for (int i = 0; i < 4; ++i)
#pragma unroll
            for (int j = 0; j < 4; ++j)
                acc[i][j] = MFMA16(af[i], bf[j], acc[i][j]);
        __builtin_amdgcn_s_setprio(0);

        if (t + 2 < NT) asm volatile("s_waitcnt vmcnt(3)" ::: "memory");  // t+1 landed
        else            asm volatile("s_waitcnt vmcnt(0)" ::: "memory");
        __builtin_amdgcn_s_barrier();
        asm volatile("" ::: "memory");
    }

    float2* tabf = reinterpret_cast<float2*>(sm);
    if (EPI == 0) {
        // RoPE table over dead LDS: 128 t x 32 d2 float2 = 32 KiB
        const int t0 = (bm & 31) * 128;
        for (int e = tid; e < 4096; e += 512) {
            int tl = e >> 5, d2 = e & 31;
            float f = (float)(t0 + tl) * exp2f(-(float)d2 * 0.41524101186092f);
            float sn, cs; __sincosf(f, &sn, &cs);
            tabf[tl * 32 + d2] = make_float2(cs, sn);
        }
        __syncthreads();
    }

#pragma unroll
    for (int i = 0; i < 4; ++i)
#pragma unroll
        for (int j = 0; j < 4; ++j)
#pragma unroll
            for (int r = 0; r < 4; ++r) {
                int row = bm * 128 + wr * 64 + i * 16 + quad * 4 + r;
                int col = bn * 256 + wc * 64 + j * 16 + l15;
                float v = acc[i][j][r];
                if (EPI == 0) {
                    float p = __shfl_xor(v, 1);
                    int t_ = row & 4095, b_ = row >> 12;
                    int hh = col >> 6, d = col & 63;
                    int tl = wr * 64 + i * 16 + quad * 4 + r;
                    float2 cspair = tabf[tl * 32 + (d >> 1)];
                    float o = (d & 1) ? (p * cspair.y + v * cspair.x)
                                      : (v * cspair.x - p * cspair.y);
                    o *= QSCALE;
                    float po = __shfl_xor(o, 1);
                    if (!(lane & 1)) {
                        unsigned int pk = (unsigned int)f2bf(o) |
                                          ((unsigned int)f2bf(po) << 16);
                        *reinterpret_cast<unsigned int*>(
                            Cb + ((size_t)((b_ * 32 + hh) * 4096 + t_)) * 64 + d) = pk;
                    }
                } else {
                    Cf[(size_t)row * 2048 + col] = v;
                }
            }
}

// ---------------- flash attention over 1024-key window ----------------
// Swapped-operand form (T12) + in-register P repack; 512-thread / 8-wave
// blocks covering 128 queries; L via MFMA ones-trick; T5 setprio.
// `base` lets the launch be split into two dispatches (diagnostic: gets the
// gemm dispatches into rocprof's top-5 by duration).
__global__ __launch_bounds__(512, 8)
void attn(const unsigned short* __restrict__ Q,
          const unsigned short* __restrict__ Kw,
          const unsigned short* __restrict__ Vt,
          unsigned short* __restrict__ O, int base) {
    const int blk  = blockIdx.x + base;
    const int qblk = blk & 31;          // 32 blocks of 128 queries
    const int bh   = blk >> 5;
    const int h    = bh & 31;
    const int b    = bh >> 5;
    const int kvh  = h >> 2;

    const int tid  = threadIdx.x;
    const int lane = tid & 63;
    const int l15  = lane & 15;
    const int quad = lane >> 4;
    const int wid  = tid >> 6;          // 0..7
    const int qt0  = qblk * 128 + wid * 16;

    const unsigned short* Qp = Q  + ((size_t)bh * 4096 + qt0) * 64;
    const unsigned short* Kp = Kw + (size_t)(b * 8 + kvh) * 1024 * 64;
    const unsigned short* Vp = Vt + (size_t)(b * 8 + kvh) * 64 * 1024;

    // [buf][frag(8) * 512 + lane*8]; frag (c*2+half) for K, (j*2+shalf) for V
    __shared__ unsigned short Ks[2][4096];
    __shared__ unsigned short Vs[2][4096];

    short8 qa0 = lds8(&Qp[l15 * 64 + quad * 8]);
    short8 qa1 = lds8(&Qp[l15 * 64 + 32 + quad * 8]);

    short8 ones;                         // bf16 1.0 x8 (A-frag of all-ones)
#pragma unroll
    for (int i = 0; i < 8; ++i) ones[i] = (short)0x3F80;

    // staging: wave w stages K frag f=w and V frag f=w
    const unsigned short* gK = Kp + (size_t)((wid >> 1) * 16 + l15) * 64
                                  + (wid & 1) * 32 + quad * 8;
    const unsigned short* gV = Vp + (size_t)((wid >> 1) * 16 + l15) * 1024
                                  + (wid & 1) * 32 + quad * 8;
    unsigned short* sK0 = &Ks[0][wid * 512];
    unsigned short* sK1 = &Ks[1][wid * 512];
    unsigned short* sV0 = &Vs[0][wid * 512];
    unsigned short* sV1 = &Vs[1][wid * 512];

    const int ntiles = (qblk < 7 ? 2 * qblk + 2 : 16);      // block-uniform
    const int nkW    = (qt0 + 16 < 1024) ? qt0 + 16 : 1024; // per-wave keys
    const int ntW    = (nkW + 63) >> 6;                     // wave's tile count
    const bool diagW = (qt0 < 1024);

    // prefetch tile 0
    g2l16(gK, sK0);
    g2l16(gV, sV0);

    floatx4 o0 = {0,0,0,0}, o1 = {0,0,0,0}, o2 = {0,0,0,0}, o3 = {0,0,0,0};
    floatx4 La = {0,0,0,0};
    float m = -INFINITY;

    for (int it = 0; it < ntiles; ++it) {
        __syncthreads();                         // staging of tile `it` complete
        const int cur = it & 1;
        if (it + 1 < ntiles) {                   // prefetch next into other buffer
            g2l16(gK + (it + 1) * 4096, cur ? sK0 : sK1);
            g2l16(gV + (it + 1) * 64,   cur ? sV0 : sV1);
        }
        if (it >= ntW) continue;                 // wave done (barriers stay uniform)
        const int s0 = it << 6;
        const unsigned short* Kc = Ks[cur];
        const unsigned short* Vc = Vs[cur];

        // S^T = K·Q^T: lane holds S[key = s0 + c*16 + quad*4 + r][query = qt0 + l15]
        floatx4 sS[4];
        __builtin_amdgcn_s_setprio(1);
#pragma unroll
        for (int c = 0; c < 4; ++c) {
            floatx4 z = {0, 0, 0, 0};
            z = MFMA16(lds8(Kc + c * 1024 + lane * 8), qa0, z);
            z = MFMA16(lds8(Kc + c * 1024 + 512 + lane * 8), qa1, z);
            sS[c] = z;
        }
        __builtin_amdgcn_s_setprio(0);

        const bool last = (it == ntW - 1);
        bool skipHi = false;
        if (last && diagW) {                     // diagonal tile: causal mask
#pragma unroll
            for (int c = 0; c < 4; ++c)
#pragma unroll
                for (int r = 0; r < 4; ++r)
                    if (s0 + c * 16 + quad * 4 + r > qt0 + l15) sS[c][r] = -INFINITY;
            skipHi = (nkW - s0 <= 32);
        }

        // per-query tile max: max3 tree + quad reduce (keys live on quad bits)
        float t0 = fmaxf(fmaxf(sS[0][0], sS[0][1]), fmaxf(sS[0][2], sS[0][3]));
        float t1 = fmaxf(fmaxf(sS[1][0], sS[1][1]), fmaxf(sS[1][2], sS[1][3]));
        float t2 = fmaxf(fmaxf(sS[2][0], sS[2][1]), fmaxf(sS[2][2], sS[2][3]));
        float t3 = fmaxf(fmaxf(sS[3][0], sS[3][1]), fmaxf(sS[3][2], sS[3][3]));
        float mx = fmaxf(fmaxf(t0, t1), fmaxf(t2, t3));
        mx = fmaxf(mx, __shfl_xor(mx, 16));
        mx = fmaxf(mx, __shfl_xor(mx, 32));      // quad-uniform per query l15

        // defer-max (T13): only rescale when tile max exceeds m by > 8
        if (!__all(mx <= m + 8.0f)) {
            const float mn = fmaxf(m, mx);       // quad-uniform per query
            const float alpha = exp2f(m - mn);   // m=-inf first tile -> alpha=0
            m = mn;
            o0 *= alpha; o1 *= alpha; o2 *= alpha; o3 *= alpha;
            La *= alpha;
        }

        float p[4][4];
#pragma unroll
        for (int c = 0; c < 4; ++c)
#pragma unroll
            for (int r = 0; r < 4; ++r) p[c][r] = exp2f(sS[c][r] - m);

        // in-register P repack: keys 0-31 (chunks 0,1) -> pa_lo
        unsigned int a0 = cvtpk(p[0][0], p[0][1]);
        unsigned int a1 = cvtpk(p[0][2], p[0][3]);
        unsigned int a2 = cvtpk(p[1][0], p[1][1]);
        unsigned int a3 = cvtpk(p[1][2], p[1][3]);
        pl32swap(a0, a2); pl32swap(a1, a3);
        pl16swap(a0, a2); pl16swap(a1, a3);
        uintx4 tlo = {a0, a1, a2, a3};
        short8 pa_lo = __builtin_bit_cast(short8, tlo);

        // O^T += V^T · P^T ; L += ones · P^T (full 32-key sum per query)
        __builtin_amdgcn_s_setprio(1);
        o0 = MFMA16(lds8(Vc + 0 * 512 + lane * 8), pa_lo, o0);
        o1 = MFMA16(lds8(Vc + 2 * 512 + lane * 8), pa_lo, o1);
        o2 = MFMA16(lds8(Vc + 4 * 512 + lane * 8), pa_lo, o2);
        o3 = MFMA16(lds8(Vc + 6 * 512 + lane * 8), pa_lo, o3);
        La = MFMA16(ones, pa_lo, La);
        __builtin_amdgcn_s_setprio(0);
        if (!skipHi) {
            // keys 32-63 (chunks 2,3) -> pa_hi
            unsigned int b0 = cvtpk(p[2][0], p[2][1]);
            unsigned int b1 = cvtpk(p[2][2], p[2][3]);
            unsigned int b2 = cvtpk(p[3][0], p[3][1]);
            unsigned int b3 = cvtpk(p[3][2], p[3][3]);
            pl32swap(b0, b2); pl32swap(b1, b3);
            pl16swap(b0, b2); pl16swap(b1, b3);
            uintx4 thi = {b0, b1, b2, b3};
            short8 pa_hi = __builtin_bit_cast(short8, thi);
            __builtin_amdgcn_s_setprio(1);
            o0 = MFMA16(lds8(Vc + 1 * 512 + lane * 8), pa_hi, o0);
            o1 = MFMA16(lds8(Vc + 3 * 512 + lane * 8), pa_hi, o1);
            o2 = MFMA16(lds8(Vc + 5 * 512 + lane * 8), pa_hi, o2);
            o3 = MFMA16(lds8(Vc + 7 * 512 + lane * 8), pa_hi, o3);
            La = MFMA16(ones, pa_hi, La);
            __builtin_amdgcn_s_setprio(0);
        }
    }

    const float inv = 1.f / La[0];      // all 4 entries equal (full key sum)

    // O^T layout: lane holds O[q = qt0+l15][d = j*16 + quad*4 + r] -> 8B stores
    unsigned short* Op = O + (size_t)b * 4096 * 2048 + (size_t)(qt0 + l15) * 2048
                           + h * 64 + quad * 4;
    uintx2 w0, w1, w2, w3;
    w0.x = cvtpk(o0[0] * inv, o0[1] * inv); w0.y = cvtpk(o0[2] * inv, o0[3] * inv);
    w1.x = cvtpk(o1[0] * inv, o1[1] * inv); w1.y = cvtpk(o1[2] * inv, o1[3] * inv);
    w2.x = cvtpk(o2[0] * inv, o2[1] * inv); w2.y = cvtpk(o2[2] * inv, o2[3] * inv);
    w3.x = cvtpk(o3[0] * inv, o3[1] * inv); w3.y = cvtpk(o3[2] * inv, o3[3] * inv);
    *reinterpret_cast<uintx2*>(Op)      = w0;
    *reinterpret_cast<uintx2*>(Op + 16) = w1;
    *reinterpret_cast<uintx2*>(Op + 32) = w2;
    *reinterpret_cast<uintx2*>(Op + 48) = w3;
}

// ---------------- launch ----------------
extern "C" void kernel_launch(void* const* d_in, const int* in_sizes, int n_in,
                              void* d_out, int out_size, void* d_ws, size_t ws_size,
                              hipStream_t stream) {
    const float* x  = (const float*)d_in[0];
    const float* kc = (const float*)d_in[1];
    const float* vc = (const float*)d_in[2];
    const float* Wq = (const float*)d_in[3];
    const float* Wo = (const float*)d_in[4];
    float* out = (float*)d_out;

    char* ws = (char*)d_ws;
    unsigned short* Xb  = (unsigned short*)(ws);              // 33,554,432 B (reused as O)
    unsigned short* Qb  = (unsigned short*)(ws + 33554432);   // 33,554,432 B
    unsigned short* Wqb = (unsigned short*)(ws + 67108864);   //  8,388,608 B
    unsigned short* Wob = (unsigned short*)(ws + 75497472);   //  8,388,608 B
    unsigned short* Kwb = (unsigned short*)(ws + 83886080);   //  2,097,152 B
    unsigned short* Vtb = (unsigned short*)(ws + 85983232);   //  2,097,152 B

    cvt_bf16<<<16384, 256, 0, stream>>>(x,  Xb,  4194304);
    cvt_bf16<<<4096,  256, 0, stream>>>(Wq, Wqb, 1048576);
    cvt_bf16<<<4096,  256, 0, stream>>>(Wo, Wob, 1048576);
    prep_k<<<1024, 256, 0, stream>>>(kc, Kwb);
    prep_v<<<256, 256, 0, stream>>>(vc, Vtb);

    gemm128<0><<<512, 512, 0, stream>>>(Xb, Wqb, nullptr, Qb);   // Q + RoPE (pre-scaled)
    attn<<<1024, 512, 0, stream>>>(Qb, Kwb, Vtb, Xb, 0);         // b = 0
    attn<<<1024, 512, 0, stream>>>(Qb, Kwb, Vtb, Xb, 1024);      // b = 1
    gemm128<1><<<512, 512, 0, stream>>>(Xb, Wob, out, nullptr);  // out proj
}

// Round 10
// 486.510 us; speedup vs baseline: 1.0216x; 1.0216x over previous
//
#include <hip/hip_runtime.h>
#include <math.h>

typedef __attribute__((ext_vector_type(8))) short short8;
typedef __attribute__((ext_vector_type(4))) float floatx4;
typedef __attribute__((ext_vector_type(4))) unsigned int uintx4;
typedef __attribute__((ext_vector_type(2))) unsigned int uintx2;

#define MFMA16(a, b, c) __builtin_amdgcn_mfma_f32_16x16x32_bf16((a), (b), (c), 0, 0, 0)

// log2(e) * (1/sqrt(64)) — folded into Q so attention works in exp2 domain
#define QSCALE 0.18033688011112042f

__device__ __forceinline__ unsigned short f2bf(float x) {
    unsigned int u = __float_as_uint(x);
    u += 0x7fffu + ((u >> 16) & 1u);   // round-to-nearest-even
    return (unsigned short)(u >> 16);
}

__device__ __forceinline__ short8 lds8(const unsigned short* p) {
    return *reinterpret_cast<const short8*>(p);
}

// async global->LDS, 16B per lane; LDS dest = wave-uniform base + lane*16
__device__ __forceinline__ void g2l16(const unsigned short* g, unsigned short* l) {
    __builtin_amdgcn_global_load_lds(
        (const __attribute__((address_space(1))) unsigned int*)g,
        (__attribute__((address_space(3))) unsigned int*)l,
        16, 0, 0);
}

// pack two f32 -> bf16x2 dword (RNE): low = a, high = b
__device__ __forceinline__ unsigned int cvtpk(float a, float b) {
    unsigned int r;
    asm("v_cvt_pk_bf16_f32 %0, %1, %2" : "=v"(r) : "v"(a), "v"(b));
    return r;
}

// swap lanes[32:63] of a with lanes[0:31] of b (both modified)
__device__ __forceinline__ void pl32swap(unsigned int& a, unsigned int& b) {
    asm("v_permlane32_swap_b32 %0, %1" : "+v"(a), "+v"(b));
}

// swap odd 16-lane groups of a with even 16-lane groups of b (both modified)
__device__ __forceinline__ void pl16swap(unsigned int& a, unsigned int& b) {
    asm("v_permlane16_swap_b32 %0, %1" : "+v"(a), "+v"(b));
}

// ---------------- prep: fp32 -> bf16 convert (vectorized) ----------------
__global__ void cvt_bf16(const float* __restrict__ src, unsigned short* __restrict__ dst, int n4) {
    int i = blockIdx.x * blockDim.x + threadIdx.x;
    if (i >= n4) return;
    float4 v = reinterpret_cast<const float4*>(src)[i];
    ushort4 o;
    o.x = f2bf(v.x); o.y = f2bf(v.y); o.z = f2bf(v.z); o.w = f2bf(v.w);
    reinterpret_cast<ushort4*>(dst)[i] = o;
}

// ---------------- prep: K window convert (coalesced both sides) ----------------
__global__ void prep_k(const float* __restrict__ kc, unsigned short* __restrict__ Kw) {
    int i = blockIdx.x * blockDim.x + threadIdx.x;   // 0 .. 262143
    int d4  = (i & 15) * 4;
    int s   = (i >> 4) & 1023;
    int bkv = i >> 14;
    size_t src = ((size_t)bkv * 4096 + 3072 + s) * 64 + d4;
    float4 kv = *reinterpret_cast<const float4*>(kc + src);
    ushort4 ko;
    ko.x = f2bf(kv.x); ko.y = f2bf(kv.y); ko.z = f2bf(kv.z); ko.w = f2bf(kv.w);
    *reinterpret_cast<ushort4*>(Kw + ((size_t)bkv * 1024 + s) * 64 + d4) = ko;
}

// ---------------- prep: V window transpose via LDS tile ----------------
__global__ void prep_v(const float* __restrict__ vc, unsigned short* __restrict__ Vt) {
    __shared__ unsigned short tl[64][72];
    const int bkv = blockIdx.x >> 4;
    const int s0  = (blockIdx.x & 15) * 64;
    const int t   = threadIdx.x;
    const int sl  = t >> 2;
    const int dq  = (t & 3) * 16;
    const float* src = vc + ((size_t)bkv * 4096 + 3072 + s0 + sl) * 64 + dq;
    float4 v0 = reinterpret_cast<const float4*>(src)[0];
    float4 v1 = reinterpret_cast<const float4*>(src)[1];
    float4 v2 = reinterpret_cast<const float4*>(src)[2];
    float4 v3 = reinterpret_cast<const float4*>(src)[3];
    tl[dq +  0][sl] = f2bf(v0.x); tl[dq +  1][sl] = f2bf(v0.y);
    tl[dq +  2][sl] = f2bf(v0.z); tl[dq +  3][sl] = f2bf(v0.w);
    tl[dq +  4][sl] = f2bf(v1.x); tl[dq +  5][sl] = f2bf(v1.y);
    tl[dq +  6][sl] = f2bf(v1.z); tl[dq +  7][sl] = f2bf(v1.w);
    tl[dq +  8][sl] = f2bf(v2.x); tl[dq +  9][sl] = f2bf(v2.y);
    tl[dq + 10][sl] = f2bf(v2.z); tl[dq + 11][sl] = f2bf(v2.w);
    tl[dq + 12][sl] = f2bf(v3.x); tl[dq + 13][sl] = f2bf(v3.y);
    tl[dq + 14][sl] = f2bf(v3.z); tl[dq + 15][sl] = f2bf(v3.w);
    __syncthreads();
    const int dl = t >> 2;
    const int sc = (t & 3) * 16;
    unsigned short* dst = Vt + ((size_t)bkv * 64 + dl) * 1024 + s0 + sc;
    short8 x0 = *reinterpret_cast<const short8*>(&tl[dl][sc]);
    short8 x1 = *reinterpret_cast<const short8*>(&tl[dl][sc + 8]);
    *reinterpret_cast<short8*>(dst)     = x0;
    *reinterpret_cast<short8*>(dst + 8) = x1;
}

// ---------------- bf16 MFMA GEMM, 128x256 tile, BK=32, triple-buffered ----------------
// R9 counters: MfmaUtil 25%, VALU 15%, ~2400 cyc/iter stall — the depth-1.5
// prefetch can't cover the ~700-900 cyc L3-hit latency of the A-tile loads
// (A is re-fetched once per XCD: FETCH 139 MB ~ 4x inputs). This round:
// 3 LDS buffers (72 KiB, still 2 blocks/CU) with prefetch distance 3 —
// STAGE(t+3) into buf[t%3] right after its reads retire; iteration-end wait
// is vmcnt(6) (retires t+1 only, keeps t+2/t+3 in flight) -> ~2.5 iters of
// latency cover. Fragment-order LDS: conflict-free g2l16/ds_read pair.
template <int EPI>
__global__ __launch_bounds__(512, 4)
void gemm128(const unsigned short* __restrict__ A,
             const unsigned short* __restrict__ Bt,
             float* __restrict__ Cf,
             unsigned short* __restrict__ Cb) {
    constexpr int K  = 2048;
    constexpr int NT = 64;                        // K / 32
    __shared__ __align__(16) unsigned short sm[36864];   // 3 bufs x 24 KiB = 72 KiB

    const int tid  = threadIdx.x;
    const int lane = tid & 63;
    const int l15  = lane & 15;
    const int quad = lane >> 4;
    const int wid  = tid >> 6;                    // 0..7
    const int wr   = wid >> 2;                    // 0..1 (M half: 64 rows)
    const int wc   = wid & 3;                     // 0..3 (N quarter: 64 cols)

    const int bn = blockIdx.x & 7;                // XCD-friendly: B-panel per XCD (1 MB, L2)
    const int bm = blockIdx.x >> 3;               // 0..63

    const unsigned short* gA0 = A  + (size_t)(bm * 128 + wid * 16 + l15) * K + quad * 8;
    const unsigned short* gB0 = Bt + (size_t)(bn * 256 + wid * 16 + l15) * K + quad * 8;
    const unsigned short* gB1 = gB0 + (size_t)128 * K;

    auto STAGE = [&](int t) {
        unsigned short* dst = sm + (t % 3) * 12288;
        const int off = t * 32;
        g2l16(gA0 + off, dst + wid * 512);                 // A frags 0..7
        g2l16(gB0 + off, dst + 4096 + wid * 512);          // B frags 0..7
        g2l16(gB1 + off, dst + 8192 + wid * 512);          // B frags 8..15
    };

    floatx4 acc[4][4];
#pragma unroll
    for (int i = 0; i < 4; ++i)
#pragma unroll
        for (int j = 0; j < 4; ++j) acc[i][j] = floatx4{0, 0, 0, 0};

    STAGE(0);
    STAGE(1);
    STAGE(2);
    asm volatile("s_waitcnt vmcnt(6)" ::: "memory");   // tile 0 landed
    __builtin_amdgcn_s_barrier();
    asm volatile("" ::: "memory");

    for (int t = 0; t < NT; ++t) {
        const unsigned short* cb = sm + (t % 3) * 12288;

        short8 af[4], bf[4];
#pragma unroll
        for (int i = 0; i < 4; ++i)
            af[i] = lds8(cb + (wr * 4 + i) * 512 + lane * 8);
#pragma unroll
        for (int j = 0; j < 4; ++j)
            bf[j] = lds8(cb + 4096 + (wc * 4 + j) * 512 + lane * 8);

        asm volatile("s_waitcnt lgkmcnt(0)" ::: "memory");
        __builtin_amdgcn_s_barrier();             // all reads of tile t retired
        asm volatile("" ::: "memory");

        if (t + 3 < NT) STAGE(t + 3);             // overwrite buf[t%3] (just freed)

        __builtin_amdgcn_s_setprio(1);
#pragma unroll
        for (int i = 0; i < 4; ++i)
#pragma unroll
            for (int j = 0; j < 4; ++j)
                acc[i][j] = MFMA16(af[i], bf[j], acc[i][j]);
        __builtin_amdgcn_s_setprio(0);

        if (t + 3 < NT)      asm volatile("s_waitcnt vmcnt(6)" ::: "memory"); // t+1 landed
        else if (t + 2 < NT) asm volatile("s_waitcnt vmcnt(3)" ::: "memory");
        else                 asm volatile("s_waitcnt vmcnt(0)" ::: "memory");
        __builtin_amdgcn_s_barrier();
        asm volatile("" ::: "memory");
    }

    float2* tabf = reinterpret_cast<float2*>(sm);
    if (EPI == 0) {
        // RoPE table over dead LDS: 128 t x 32 d2 float2 = 32 KiB
        const int t0 = (bm & 31) * 128;
        for (int e = tid; e < 4096; e += 512) {
            int tl = e >> 5, d2 = e & 31;
            float f = (float)(t0 + tl) * exp2f(-(float)d2 * 0.41524101186092f);
            float sn, cs; __sincosf(f, &sn, &cs);
            tabf[tl * 32 + d2] = make_float2(cs, sn);
        }
        __syncthreads();
    }

#pragma unroll
    for (int i = 0; i < 4; ++i)
#pragma unroll
        for (int j = 0; j < 4; ++j)
#pragma unroll
            for (int r = 0; r < 4; ++r) {
                int row = bm * 128 + wr * 64 + i * 16 + quad * 4 + r;
                int col = bn * 256 + wc * 64 + j * 16 + l15;
                float v = acc[i][j][r];
                if (EPI == 0) {
                    float p = __shfl_xor(v, 1);
                    int t_ = row & 4095, b_ = row >> 12;
                    int hh = col >> 6, d = col & 63;
                    int tl = wr * 64 + i * 16 + quad * 4 + r;
                    float2 cspair = tabf[tl * 32 + (d >> 1)];
                    float o = (d & 1) ? (p * cspair.y + v * cspair.x)
                                      : (v * cspair.x - p * cspair.y);
                    o *= QSCALE;
                    float po = __shfl_xor(o, 1);
                    if (!(lane & 1)) {
                        unsigned int pk = (unsigned int)f2bf(o) |
                                          ((unsigned int)f2bf(po) << 16);
                        *reinterpret_cast<unsigned int*>(
                            Cb + ((size_t)((b_ * 32 + hh) * 4096 + t_)) * 64 + d) = pk;
                    }
                } else {
                    Cf[(size_t)row * 2048 + col] = v;
                }
            }
}

// ---------------- flash attention over 1024-key window ----------------
// Swapped-operand form (T12) + in-register P repack; 512-thread / 8-wave
// blocks covering 128 queries; L via MFMA ones-trick; T5 setprio.
// Single 2048-block dispatch (R9's 2-dispatch split regressed: tail underfill).
__global__ __launch_bounds__(512, 8)
void attn(const unsigned short* __restrict__ Q,
          const unsigned short* __restrict__ Kw,
          const unsigned short* __restrict__ Vt,
          unsigned short* __restrict__ O) {
    const int blk  = blockIdx.x;
    const int qblk = blk & 31;          // 32 blocks of 128 queries
    const int bh   = blk >> 5;
    const int h    = bh & 31;
    const int b    = bh >> 5;
    const int kvh  = h >> 2;

    const int tid  = threadIdx.x;
    const int lane = tid & 63;
    const int l15  = lane & 15;
    const int quad = lane >> 4;
    const int wid  = tid >> 6;          // 0..7
    const int qt0  = qblk * 128 + wid * 16;

    const unsigned short* Qp = Q  + ((size_t)bh * 4096 + qt0) * 64;
    const unsigned short* Kp = Kw + (size_t)(b * 8 + kvh) * 1024 * 64;
    const unsigned short* Vp = Vt + (size_t)(b * 8 + kvh) * 64 * 1024;

    // [buf][frag(8) * 512 + lane*8]; frag (c*2+half) for K, (j*2+shalf) for V
    __shared__ unsigned short Ks[2][4096];
    __shared__ unsigned short Vs[2][4096];

    short8 qa0 = lds8(&Qp[l15 * 64 + quad * 8]);
    short8 qa1 = lds8(&Qp[l15 * 64 + 32 + quad * 8]);

    short8 ones;                         // bf16 1.0 x8 (A-frag of all-ones)
#pragma unroll
    for (int i = 0; i < 8; ++i) ones[i] = (short)0x3F80;

    // staging: wave w stages K frag f=w and V frag f=w
    const unsigned short* gK = Kp + (size_t)((wid >> 1) * 16 + l15) * 64
                                  + (wid & 1) * 32 + quad * 8;
    const unsigned short* gV = Vp + (size_t)((wid >> 1) * 16 + l15) * 1024
                                  + (wid & 1) * 32 + quad * 8;
    unsigned short* sK0 = &Ks[0][wid * 512];
    unsigned short* sK1 = &Ks[1][wid * 512];
    unsigned short* sV0 = &Vs[0][wid * 512];
    unsigned short* sV1 = &Vs[1][wid * 512];

    const int ntiles = (qblk < 7 ? 2 * qblk + 2 : 16);      // block-uniform
    const int nkW    = (qt0 + 16 < 1024) ? qt0 + 16 : 1024; // per-wave keys
    const int ntW    = (nkW + 63) >> 6;                     // wave's tile count
    const bool diagW = (qt0 < 1024);

    // prefetch tile 0
    g2l16(gK, sK0);
    g2l16(gV, sV0);

    floatx4 o0 = {0,0,0,0}, o1 = {0,0,0,0}, o2 = {0,0,0,0}, o3 = {0,0,0,0};
    floatx4 La = {0,0,0,0};
    float m = -INFINITY;

    for (int it = 0; it < ntiles; ++it) {
        __syncthreads();                         // staging of tile `it` complete
        const int cur = it & 1;
        if (it + 1 < ntiles) {                   // prefetch next into other buffer
            g2l16(gK + (it + 1) * 4096, cur ? sK0 : sK1);
            g2l16(gV + (it + 1) * 64,   cur ? sV0 : sV1);
        }
        if (it >= ntW) continue;                 // wave done (barriers stay uniform)
        const int s0 = it << 6;
        const unsigned short* Kc = Ks[cur];
        const unsigned short* Vc = Vs[cur];

        // S^T = K·Q^T: lane holds S[key = s0 + c*16 + quad*4 + r][query = qt0 + l15]
        floatx4 sS[4];
        __builtin_amdgcn_s_setprio(1);
#pragma unroll
        for (int c = 0; c < 4; ++c) {
            floatx4 z = {0, 0, 0, 0};
            z = MFMA16(lds8(Kc + c * 1024 + lane * 8), qa0, z);
            z = MFMA16(lds8(Kc + c * 1024 + 512 + lane * 8), qa1, z);
            sS[c] = z;
        }
        __builtin_amdgcn_s_setprio(0);

        const bool last = (it == ntW - 1);
        bool skipHi = false;
        if (last && diagW) {                     // diagonal tile: causal mask
#pragma unroll
            for (int c = 0; c < 4; ++c)
#pragma unroll
                for (int r = 0; r < 4; ++r)
                    if (s0 + c * 16 + quad * 4 + r > qt0 + l15) sS[c][r] = -INFINITY;
            skipHi = (nkW - s0 <= 32);
        }

        // per-query tile max: max3 tree + quad reduce (keys live on quad bits)
        float t0 = fmaxf(fmaxf(sS[0][0], sS[0][1]), fmaxf(sS[0][2], sS[0][3]));
        float t1 = fmaxf(fmaxf(sS[1][0], sS[1][1]), fmaxf(sS[1][2], sS[1][3]));
        float t2 = fmaxf(fmaxf(sS[2][0], sS[2][1]), fmaxf(sS[2][2], sS[2][3]));
        float t3 = fmaxf(fmaxf(sS[3][0], sS[3][1]), fmaxf(sS[3][2], sS[3][3]));
        float mx = fmaxf(fmaxf(t0, t1), fmaxf(t2, t3));
        mx = fmaxf(mx, __shfl_xor(mx, 16));
        mx = fmaxf(mx, __shfl_xor(mx, 32));      // quad-uniform per query l15

        // defer-max (T13): only rescale when tile max exceeds m by > 8
        if (!__all(mx <= m + 8.0f)) {
            const float mn = fmaxf(m, mx);       // quad-uniform per query
            const float alpha = exp2f(m - mn);   // m=-inf first tile -> alpha=0
            m = mn;
            o0 *= alpha; o1 *= alpha; o2 *= alpha; o3 *= alpha;
            La *= alpha;
        }

        float p[4][4];
#pragma unroll
        for (int c = 0; c < 4; ++c)
#pragma unroll
            for (int r = 0; r < 4; ++r) p[c][r] = exp2f(sS[c][r] - m);

        // in-register P repack: keys 0-31 (chunks 0,1) -> pa_lo
        unsigned int a0 = cvtpk(p[0][0], p[0][1]);
        unsigned int a1 = cvtpk(p[0][2], p[0][3]);
        unsigned int a2 = cvtpk(p[1][0], p[1][1]);
        unsigned int a3 = cvtpk(p[1][2], p[1][3]);
        pl32swap(a0, a2); pl32swap(a1, a3);
        pl16swap(a0, a2); pl16swap(a1, a3);
        uintx4 tlo = {a0, a1, a2, a3};
        short8 pa_lo = __builtin_bit_cast(short8, tlo);

        // O^T += V^T · P^T ; L += ones · P^T (full 32-key sum per query)
        __builtin_amdgcn_s_setprio(1);
        o0 = MFMA16(lds8(Vc + 0 * 512 + lane * 8), pa_lo, o0);
        o1 = MFMA16(lds8(Vc + 2 * 512 + lane * 8), pa_lo, o1);
        o2 = MFMA16(lds8(Vc + 4 * 512 + lane * 8), pa_lo, o2);
        o3 = MFMA16(lds8(Vc + 6 * 512 + lane * 8), pa_lo, o3);
        La = MFMA16(ones, pa_lo, La);
        __builtin_amdgcn_s_setprio(0);
        if (!skipHi) {
            // keys 32-63 (chunks 2,3) -> pa_hi
            unsigned int b0 = cvtpk(p[2][0], p[2][1]);
            unsigned int b1 = cvtpk(p[2][2], p[2][3]);
            unsigned int b2 = cvtpk(p[3][0], p[3][1]);
            unsigned int b3 = cvtpk(p[3][2], p[3][3]);
            pl32swap(b0, b2); pl32swap(b1, b3);
            pl16swap(b0, b2); pl16swap(b1, b3);
            uintx4 thi = {b0, b1, b2, b3};
            short8 pa_hi = __builtin_bit_cast(short8, thi);
            __builtin_amdgcn_s_setprio(1);
            o0 = MFMA16(lds8(Vc + 1 * 512 + lane * 8), pa_hi, o0);
            o1 = MFMA16(lds8(Vc + 3 * 512 + lane * 8), pa_hi, o1);
            o2 = MFMA16(lds8(Vc + 5 * 512 + lane * 8), pa_hi, o2);
            o3 = MFMA16(lds8(Vc + 7 * 512 + lane * 8), pa_hi, o3);
            La = MFMA16(ones, pa_hi, La);
            __builtin_amdgcn_s_setprio(0);
        }
    }

    const float inv = 1.f / La[0];      // all 4 entries equal (full key sum)

    // O^T layout: lane holds O[q = qt0+l15][d = j*16 + quad*4 + r] -> 8B stores
    unsigned short* Op = O + (size_t)b * 4096 * 2048 + (size_t)(qt0 + l15) * 2048
                           + h * 64 + quad * 4;
    uintx2 w0, w1, w2, w3;
    w0.x = cvtpk(o0[0] * inv, o0[1] * inv); w0.y = cvtpk(o0[2] * inv, o0[3] * inv);
    w1.x = cvtpk(o1[0] * inv, o1[1] * inv); w1.y = cvtpk(o1[2] * inv, o1[3] * inv);
    w2.x = cvtpk(o2[0] * inv, o2[1] * inv); w2.y = cvtpk(o2[2] * inv, o2[3] * inv);
    w3.x = cvtpk(o3[0] * inv, o3[1] * inv); w3.y = cvtpk(o3[2] * inv, o3[3] * inv);
    *reinterpret_cast<uintx2*>(Op)      = w0;
    *reinterpret_cast<uintx2*>(Op + 16) = w1;
    *reinterpret_cast<uintx2*>(Op + 32) = w2;
    *reinterpret_cast<uintx2*>(Op + 48) = w3;
}

// ---------------- launch ----------------
extern "C" void kernel_launch(void* const* d_in, const int* in_sizes, int n_in,
                              void* d_out, int out_size, void* d_ws, size_t ws_size,
                              hipStream_t stream) {
    const float* x  = (const float*)d_in[0];
    const float* kc = (const float*)d_in[1];
    const float* vc = (const float*)d_in[2];
    const float* Wq = (const float*)d_in[3];
    const float* Wo = (const float*)d_in[4];
    float* out = (float*)d_out;

    char* ws = (char*)d_ws;
    unsigned short* Xb  = (unsigned short*)(ws);              // 33,554,432 B (reused as O)
    unsigned short* Qb  = (unsigned short*)(ws + 33554432);   // 33,554,432 B
    unsigned short* Wqb = (unsigned short*)(ws + 67108864);   //  8,388,608 B
    unsigned short* Wob = (unsigned short*)(ws + 75497472);   //  8,388,608 B
    unsigned short* Kwb = (unsigned short*)(ws + 83886080);   //  2,097,152 B
    unsigned short* Vtb = (unsigned short*)(ws + 85983232);   //  2,097,152 B

    cvt_bf16<<<16384, 256, 0, stream>>>(x,  Xb,  4194304);
    cvt_bf16<<<4096,  256, 0, stream>>>(Wq, Wqb, 1048576);
    cvt_bf16<<<4096,  256, 0, stream>>>(Wo, Wob, 1048576);
    prep_k<<<1024, 256, 0, stream>>>(kc, Kwb);
    prep_v<<<256, 256, 0, stream>>>(vc, Vtb);

    gemm128<0><<<512, 512, 0, stream>>>(Xb, Wqb, nullptr, Qb);   // Q + RoPE (pre-scaled)
    attn<<<2048, 512, 0, stream>>>(Qb, Kwb, Vtb, Xb);            // O -> Xb
    gemm128<1><<<512, 512, 0, stream>>>(Xb, Wob, out, nullptr);  // out proj
}